// Round 1
// baseline (1853.309 us; speedup 1.0000x reference)
//
#include <hip/hip_runtime.h>
#include <math.h>

#define N_TOK 32768
#define F_DIM 1024
#define H_DIM 64

typedef __attribute__((ext_vector_type(8))) short short8;
typedef __attribute__((ext_vector_type(4))) float floatx4;

// round-to-nearest-even f32 -> bf16 bits
__device__ __forceinline__ short f2bf(float f) {
  unsigned u = __builtin_bit_cast(unsigned, f);
  unsigned r = (u + 0x7fffu + ((u >> 16) & 1u)) >> 16;
  return (short)r;
}

__device__ __forceinline__ float softplusf(float v) {
  float a = fabsf(v);
  float r = log1pf(expf(-a));
  return v > 0.f ? v + r : r;
}

// Build bf16 transposed weights in workspace:
//   w1t[m][h][f] = bf16(W1[m][f][h])   (B^T layout for fc1, rows are MFMA-B cols)
//   w2t[m][f][h] = bf16(W2[m][h][f])   (B^T layout for fc2)
__global__ void prep_weights(const float* __restrict__ W1, const float* __restrict__ W2,
                             short* __restrict__ w1t, short* __restrict__ w2t) {
  int idx = blockIdx.x * blockDim.x + threadIdx.x;
  if (idx >= 6 * 64 * 1024) return;
  // w1t: idx = (m*64+h)*1024 + f
  {
    int f = idx & 1023;
    int mh = idx >> 10;
    int h = mh & 63;
    int m = mh >> 6;
    w1t[idx] = f2bf(W1[(m * 1024 + f) * 64 + h]);
  }
  // w2t: idx = (m*1024+f)*64 + h
  {
    int h = idx & 63;
    int mf = idx >> 6;
    int f = mf & 1023;
    int m = mf >> 10;
    w2t[idx] = f2bf(W2[(m * 64 + h) * 1024 + f]);
  }
}

// Branches 0..4: per 64-row tile, fc1 (K=1024 -> 320 cols) then fc2 (K=64 -> 1024 cols)
// with fused +x +B2 epilogue and activation. Writes d_out regions 0..4.
__global__ __launch_bounds__(256) void k_fc_branches(
    const float* __restrict__ x, const short* __restrict__ w1t,
    const float* __restrict__ b1, const short* __restrict__ w2t,
    const float* __restrict__ b2, float* __restrict__ out) {
  __shared__ short hlds[64 * 328];  // h tile, row-major, stride 328 (16B-aligned rows)

  const int lane = threadIdx.x & 63;
  const int wv = threadIdx.x >> 6;   // wave 0..3 -> 16-row subtile
  const int m16 = lane & 15;
  const int quad = lane >> 4;
  const int row0 = blockIdx.x * 64 + wv * 16;

  // ---- Phase A: h[5 branches] = relu(x @ W1cat + B1): acc over 20 col-tiles ----
  floatx4 acc[20];
#pragma unroll
  for (int i = 0; i < 20; i++) acc[i] = (floatx4){0.f, 0.f, 0.f, 0.f};

  const float* xrow = x + (size_t)(row0 + m16) * F_DIM;
  for (int kk = 0; kk < 32; kk++) {
    const int k0 = kk * 32 + quad * 8;
    float4 xa = *(const float4*)(xrow + k0);
    float4 xb = *(const float4*)(xrow + k0 + 4);
    short8 a = {f2bf(xa.x), f2bf(xa.y), f2bf(xa.z), f2bf(xa.w),
                f2bf(xb.x), f2bf(xb.y), f2bf(xb.z), f2bf(xb.w)};
#pragma unroll
    for (int ct = 0; ct < 20; ct++) {
      short8 bf = *(const short8*)(w1t + (ct * 16 + m16) * 1024 + k0);
      acc[ct] = __builtin_amdgcn_mfma_f32_16x16x32_bf16(a, bf, acc[ct], 0, 0, 0);
    }
  }

  // relu + bias -> LDS (bf16). C/D layout: col = ct*16+m16, row = quad*4+r.
#pragma unroll
  for (int ct = 0; ct < 20; ct++) {
    const int c = ct * 16 + m16;          // c = branch*64 + h, matches B1 flat index
    const float bias = b1[c];
#pragma unroll
    for (int r = 0; r < 4; r++) {
      float v = acc[ct][r] + bias;
      v = v > 0.f ? v : 0.f;
      hlds[(wv * 16 + quad * 4 + r) * 328 + c] = f2bf(v);
    }
  }
  __syncthreads();

  // ---- Phase B: per branch, y = x + h@W2 + B2 (K=64), activation, store ----
  for (int b = 0; b < 5; b++) {
    const short* hrow = &hlds[(wv * 16 + m16) * 328 + b * 64];
    short8 a0 = *(const short8*)(hrow + quad * 8);
    short8 a1 = *(const short8*)(hrow + 32 + quad * 8);
    const short* w2b = w2t + b * (F_DIM * H_DIM);
    const float* b2b = b2 + b * F_DIM;
    float* ob = out + (size_t)b * N_TOK * F_DIM;
    for (int ct = 0; ct < 64; ct++) {
      const int col = ct * 16 + m16;
      short8 bf0 = *(const short8*)(w2b + col * 64 + quad * 8);
      short8 bf1 = *(const short8*)(w2b + col * 64 + 32 + quad * 8);
      floatx4 c = {0.f, 0.f, 0.f, 0.f};
      c = __builtin_amdgcn_mfma_f32_16x16x32_bf16(a0, bf0, c, 0, 0, 0);
      c = __builtin_amdgcn_mfma_f32_16x16x32_bf16(a1, bf1, c, 0, 0, 0);
      const float b2v = b2b[col];
#pragma unroll
      for (int r = 0; r < 4; r++) {
        const size_t gr = (size_t)(row0 + quad * 4 + r);
        float y = c[r] + x[gr * F_DIM + col] + b2v;
        if (b == 3) y = softplusf(y);
        else if (b == 4) y = 1.f / (1.f + expf(-y));
        ob[gr * F_DIM + col] = y;
      }
    }
  }
}

// Branch 5 (memory): out = x + q + relu(q@W1[5]+B1[5]) @ W2[5] + B2[5].
// q is read back (f32) from d_out region 2.
__global__ __launch_bounds__(256) void k_memory(
    const float* __restrict__ x, const float* __restrict__ q,
    const short* __restrict__ w1t5, const float* __restrict__ b1_5,
    const short* __restrict__ w2t5, const float* __restrict__ b2_5,
    float* __restrict__ out5) {
  __shared__ short hlds[64 * 72];

  const int lane = threadIdx.x & 63;
  const int wv = threadIdx.x >> 6;
  const int m16 = lane & 15;
  const int quad = lane >> 4;
  const int row0 = blockIdx.x * 64 + wv * 16;

  floatx4 acc[4];
#pragma unroll
  for (int i = 0; i < 4; i++) acc[i] = (floatx4){0.f, 0.f, 0.f, 0.f};

  const float* qrow = q + (size_t)(row0 + m16) * F_DIM;
  for (int kk = 0; kk < 32; kk++) {
    const int k0 = kk * 32 + quad * 8;
    float4 qa = *(const float4*)(qrow + k0);
    float4 qb = *(const float4*)(qrow + k0 + 4);
    short8 a = {f2bf(qa.x), f2bf(qa.y), f2bf(qa.z), f2bf(qa.w),
                f2bf(qb.x), f2bf(qb.y), f2bf(qb.z), f2bf(qb.w)};
#pragma unroll
    for (int ct = 0; ct < 4; ct++) {
      short8 bf = *(const short8*)(w1t5 + (ct * 16 + m16) * 1024 + k0);
      acc[ct] = __builtin_amdgcn_mfma_f32_16x16x32_bf16(a, bf, acc[ct], 0, 0, 0);
    }
  }

#pragma unroll
  for (int ct = 0; ct < 4; ct++) {
    const int c = ct * 16 + m16;
    const float bias = b1_5[c];
#pragma unroll
    for (int r = 0; r < 4; r++) {
      float v = acc[ct][r] + bias;
      v = v > 0.f ? v : 0.f;
      hlds[(wv * 16 + quad * 4 + r) * 72 + c] = f2bf(v);
    }
  }
  __syncthreads();

  const short* hrow = &hlds[(wv * 16 + m16) * 72];
  short8 a0 = *(const short8*)(hrow + quad * 8);
  short8 a1 = *(const short8*)(hrow + 32 + quad * 8);
  for (int ct = 0; ct < 64; ct++) {
    const int col = ct * 16 + m16;
    short8 bf0 = *(const short8*)(w2t5 + col * 64 + quad * 8);
    short8 bf1 = *(const short8*)(w2t5 + col * 64 + 32 + quad * 8);
    floatx4 c = {0.f, 0.f, 0.f, 0.f};
    c = __builtin_amdgcn_mfma_f32_16x16x32_bf16(a0, bf0, c, 0, 0, 0);
    c = __builtin_amdgcn_mfma_f32_16x16x32_bf16(a1, bf1, c, 0, 0, 0);
    const float b2v = b2_5[col];
#pragma unroll
    for (int r = 0; r < 4; r++) {
      const size_t gr = (size_t)(row0 + quad * 4 + r);
      float y = c[r] + x[gr * F_DIM + col] + q[gr * F_DIM + col] + b2v;
      out5[gr * F_DIM + col] = y;
    }
  }
}

extern "C" void kernel_launch(void* const* d_in, const int* in_sizes, int n_in,
                              void* d_out, int out_size, void* d_ws, size_t ws_size,
                              hipStream_t stream) {
  const float* x = (const float*)d_in[0];
  const float* W1 = (const float*)d_in[1];
  const float* B1 = (const float*)d_in[2];
  const float* W2 = (const float*)d_in[3];
  const float* B2 = (const float*)d_in[4];
  float* out = (float*)d_out;

  short* w1t = (short*)d_ws;                // [6][64][1024] bf16
  short* w2t = w1t + 6 * 64 * 1024;         // [6][1024][64] bf16  (1.5 MB total ws)

  prep_weights<<<(6 * 64 * 1024 + 255) / 256, 256, 0, stream>>>(W1, W2, w1t, w2t);

  k_fc_branches<<<N_TOK / 64, 256, 0, stream>>>(x, w1t, B1, w2t, B2, out);

  const float* q = out + (size_t)2 * N_TOK * F_DIM;
  float* out5 = out + (size_t)5 * N_TOK * F_DIM;
  k_memory<<<N_TOK / 64, 256, 0, stream>>>(x, q, w1t + 5 * 64 * 1024, B1 + 5 * 64,
                                           w2t + 5 * 1024 * 64, B2 + 5 * 1024, out5);
}